// Round 10
// baseline (373.850 us; speedup 1.0000x reference)
//
#include <hip/hip_runtime.h>
#include <hip/hip_bf16.h>

#define B_   32
#define L_   2048
#define CIN  256
#define HID  512
#define TL   16
#define NLT  (L_ / TL)        // 128 tiles of 16 rows per batch
#define NTILES (B_ * NLT)     // 4096 blocks

typedef __bf16 bf16_t;
typedef __bf16 bf16x8 __attribute__((ext_vector_type(8)));
typedef __bf16 bf16x4 __attribute__((ext_vector_type(4)));
typedef float  f32x4  __attribute__((ext_vector_type(4)));

// LDS map (48 KB): A(x)@0 8K, A(y)@8K; Hx@16K 16K, Hy@32K 16K. No aliasing.
#define AX_OFF 0u
#define AY_OFF 8192u
#define HX_OFF 16384u
#define HY_OFF 32768u

// ---------------------------------------------------------------------------
// Kernel 1: cast weights fp32 -> bf16 into workspace
// ---------------------------------------------------------------------------
__global__ void cast_weights_kernel(const float* __restrict__ W1, const float* __restrict__ W2,
                                    bf16_t* __restrict__ W1b, bf16_t* __restrict__ W2b)
{
    int i = blockIdx.x * blockDim.x + threadIdx.x;
    if (i < HID * CIN) W1b[i] = (bf16_t)W1[i];
    if (i < HID * HID) W2b[i] = (bf16_t)W2[i];
}

// ---------------------------------------------------------------------------
// Kernel 2: fused project(x)+project(y), tanh*tanh, row-reduction.
// 4096 blocks x 512 thr (8 waves) on one (16-row tile). Wave w owns cols
// [w*64, w*64+64) (cj=0..3), rows 0..15 (= l15), BOTH pipes.
// acc = 32 AGPR; arch ledger ~81 < 96 headroom at the (512,4) 128-reg cap
// (the R2/R5/R6/R8/R9 lesson: 1024-thr blocks have no headroom; 512-thr
// blocks with TL=16 do). LDS 48 KB -> 2 blocks/CU: cross-block phase overlap
// hides stage-HBM and W-L2 latency under the other block's MFMA.
// Swapped-operand MFMA (D.m = H-col), biases in acc init, paired tanh.
// 2 barriers total.
// ---------------------------------------------------------------------------
__global__ __launch_bounds__(512, 4)
void fused_proj_kernel(const float* __restrict__ x, const float* __restrict__ y,
                       const bf16_t* __restrict__ W1b, const float* __restrict__ b1,
                       const bf16_t* __restrict__ W2b, const float* __restrict__ b2,
                       float* __restrict__ partial)
{
    __shared__ char U[49152];            // 48 KB

    const int tid  = threadIdx.x;
    const int lane = tid & 63;
    const int wv   = tid >> 6;           // wave 0..7
    const int l15  = lane & 15;
    const int l4   = lane >> 4;
    const int col0 = wv * 64;            // this wave's output-col base
    const int tile = blockIdx.x;

    // --- stage [16 x CIN] fp32 -> bf16, swizzled. thr 0-255 x, 256-511 y;
    // 16 thr/row, 4 float4 each (coalesced 16-thread bursts).
    {
        const int sp = tid >> 8;
        const int t8 = tid & 255;
        const int sr = t8 >> 4;          // row 0..15
        const int sq = t8 & 15;          // float4 slot
        const float4* s4 = reinterpret_cast<const float4*>(
            (sp ? y : x) + ((size_t)tile * TL + sr) * CIN);
        char* rowp = U + (sp ? AY_OFF : AX_OFF) + sr * 512;
        const unsigned swz = (unsigned)((sr & 15) << 4);
#pragma unroll
        for (int c = 0; c < 4; ++c) {
            float4 vv = s4[sq + 16 * c];
            bf16x4 h;
            h[0] = (bf16_t)vv.x; h[1] = (bf16_t)vv.y;
            h[2] = (bf16_t)vv.z; h[3] = (bf16_t)vv.w;
            *reinterpret_cast<bf16x4*>(rowp + (((unsigned)(8 * (sq + 16 * c))) ^ swz)) = h;
        }
    }
    __syncthreads();                     // B0: A(x), A(y) ready

    const unsigned fswz = (unsigned)((l15 & 15) << 4);   // fragment-row swizzle
    const unsigned fcol = ((unsigned)(l4 * 16)) ^ fswz;  // per-kk addr = base ^ (kk<<6)

    // ---- GEMM1 both pipes (shared W1 stream), bias b1 folded into acc init
    f32x4 accx[4], accy[4];              // [cj] : 32 AGPR total
#pragma unroll
    for (int cj = 0; cj < 4; ++cj) {
        float4 bv = *reinterpret_cast<const float4*>(b1 + col0 + cj * 16 + l4 * 4);
        f32x4 bi = (f32x4){bv.x, bv.y, bv.z, bv.w};
        accx[cj] = bi; accy[cj] = bi;
    }
    for (int kk = 0; kk < CIN / 32; ++kk) {
        bf16x8 w[4];
#pragma unroll
        for (int cj = 0; cj < 4; ++cj)
            w[cj] = *reinterpret_cast<const bf16x8*>(
                W1b + (size_t)(col0 + cj * 16 + l15) * CIN + kk * 32 + l4 * 8);
        const unsigned o = (unsigned)(l15 * 512) + (fcol ^ (unsigned)(kk << 6));
        bf16x8 ax = *reinterpret_cast<const bf16x8*>(U + AX_OFF + o);
        bf16x8 ay = *reinterpret_cast<const bf16x8*>(U + AY_OFF + o);
        __builtin_amdgcn_s_setprio(1);
#pragma unroll
        for (int cj = 0; cj < 4; ++cj) {
            accx[cj] = __builtin_amdgcn_mfma_f32_16x16x32_bf16(w[cj], ax, accx[cj], 0, 0, 0);
            accy[cj] = __builtin_amdgcn_mfma_f32_16x16x32_bf16(w[cj], ay, accy[cj], 0, 0, 0);
        }
        __builtin_amdgcn_s_setprio(0);
    }

    // ---- writeH: packed bf16x4 per (cj); row = l15, cols col0+cj*16+l4*4..+4
#pragma unroll
    for (int cj = 0; cj < 4; ++cj) {
        unsigned off = (unsigned)(l15 * 1024) +
                       (((unsigned)((col0 + cj * 16 + l4 * 4) * 2)) ^ fswz);
        bf16x4 px, py;
#pragma unroll
        for (int r2 = 0; r2 < 4; ++r2) {
            px[r2] = (bf16_t)accx[cj][r2];
            py[r2] = (bf16_t)accy[cj][r2];
        }
        *reinterpret_cast<bf16x4*>(U + HX_OFF + off) = px;
        *reinterpret_cast<bf16x4*>(U + HY_OFF + off) = py;
    }
    __syncthreads();                     // B1: H(x), H(y) ready

    // ---- GEMM2 both pipes (shared W2 stream), bias b2 folded into acc init
#pragma unroll
    for (int cj = 0; cj < 4; ++cj) {
        float4 bv = *reinterpret_cast<const float4*>(b2 + col0 + cj * 16 + l4 * 4);
        f32x4 bi = (f32x4){bv.x, bv.y, bv.z, bv.w};
        accx[cj] = bi; accy[cj] = bi;
    }
    for (int kk = 0; kk < HID / 32; ++kk) {
        bf16x8 w[4];
#pragma unroll
        for (int cj = 0; cj < 4; ++cj)
            w[cj] = *reinterpret_cast<const bf16x8*>(
                W2b + (size_t)(col0 + cj * 16 + l15) * HID + kk * 32 + l4 * 8);
        const unsigned o = (unsigned)(l15 * 1024) + (fcol ^ (unsigned)(kk << 6));
        bf16x8 px = *reinterpret_cast<const bf16x8*>(U + HX_OFF + o);
        bf16x8 py = *reinterpret_cast<const bf16x8*>(U + HY_OFF + o);
        __builtin_amdgcn_s_setprio(1);
#pragma unroll
        for (int cj = 0; cj < 4; ++cj) {
            accx[cj] = __builtin_amdgcn_mfma_f32_16x16x32_bf16(w[cj], px, accx[cj], 0, 0, 0);
            accy[cj] = __builtin_amdgcn_mfma_f32_16x16x32_bf16(w[cj], py, accy[cj], 0, 0, 0);
        }
        __builtin_amdgcn_s_setprio(0);
    }

    // ---- paired tanh product + reduce over the 16 rows (= l15 lanes).
    // tanh(a)tanh(b) = (Ea-1)(Eb-1)/((Ea+1)(Eb+1)), E = e^{2v} clamped.
    f32x4 psum[4];
#pragma unroll
    for (int cj = 0; cj < 4; ++cj) {
#pragma unroll
        for (int r2 = 0; r2 < 4; ++r2) {
            float a = fminf(fmaxf(accx[cj][r2], -9.0f), 9.0f);
            float c = fminf(fmaxf(accy[cj][r2], -9.0f), 9.0f);
            float Ea = exp2f(a * 2.885390081777927f);
            float Eb = exp2f(c * 2.885390081777927f);
            float num = (Ea - 1.0f) * (Eb - 1.0f);
            float den = (Ea + 1.0f) * (Eb + 1.0f);
            psum[cj][r2] = num * __builtin_amdgcn_rcpf(den);
        }
    }
#pragma unroll
    for (int cj = 0; cj < 4; ++cj)
#pragma unroll
        for (int r2 = 0; r2 < 4; ++r2) {
            float s = psum[cj][r2];
            s += __shfl_xor(s, 1);
            s += __shfl_xor(s, 2);
            s += __shfl_xor(s, 4);
            s += __shfl_xor(s, 8);
            psum[cj][r2] = s;
        }
    if (l15 == 0) {
#pragma unroll
        for (int cj = 0; cj < 4; ++cj) {
            float4 o4 = make_float4(psum[cj][0], psum[cj][1], psum[cj][2], psum[cj][3]);
            *reinterpret_cast<float4*>(partial + (size_t)tile * HID + col0 + cj * 16 + l4 * 4) = o4;
        }
    }
}

// ---------------------------------------------------------------------------
// Kernel 3: sum the 128 tile-partials per batch -> out[B][HID]
// ---------------------------------------------------------------------------
__global__ void reduce_kernel(const float* __restrict__ partial, float* __restrict__ out)
{
    int b = blockIdx.x;
    int g = threadIdx.x;             // 512 threads
    float s = 0.f;
    for (int t = 0; t < NLT; ++t)
        s += partial[((size_t)(b * NLT + t)) * HID + g];
    out[b * HID + g] = s;
}

extern "C" void kernel_launch(void* const* d_in, const int* in_sizes, int n_in,
                              void* d_out, int out_size, void* d_ws, size_t ws_size,
                              hipStream_t stream)
{
    const float* x  = (const float*)d_in[0];
    const float* y  = (const float*)d_in[1];
    const float* W1 = (const float*)d_in[2];
    const float* b1 = (const float*)d_in[3];
    const float* W2 = (const float*)d_in[4];
    const float* b2 = (const float*)d_in[5];
    float* out = (float*)d_out;

    char* ws = (char*)d_ws;
    bf16_t* W1b    = (bf16_t*)ws;                    // 256 KB
    bf16_t* W2b    = (bf16_t*)(ws + (256 << 10));    // 512 KB
    float*  partial = (float*)(ws + (768 << 10));    // 8 MB (4096 tiles x 512)

    hipLaunchKernelGGL(cast_weights_kernel, dim3(1024), dim3(256), 0, stream, W1, W2, W1b, W2b);
    hipLaunchKernelGGL(fused_proj_kernel, dim3(NTILES), dim3(512), 0, stream,
                       x, y, W1b, b1, W2b, b2, partial);
    hipLaunchKernelGGL(reduce_kernel, dim3(B_), dim3(512), 0, stream, partial, out);
}

// Round 11
// 140.578 us; speedup vs baseline: 2.6594x; 2.6594x over previous
//
#include <hip/hip_runtime.h>
#include <hip/hip_bf16.h>

#define B_   32
#define L_   2048
#define CIN  256
#define HID  512
#define TL   32
#define NTILES (B_ * L_ / TL) // 2048
#define TPB  8                // tiles per block (256 rows, never crosses batch)
#define NBLK (NTILES / TPB)   // 256 blocks = 1 per CU

typedef __bf16 bf16_t;
typedef __bf16 bf16x8 __attribute__((ext_vector_type(8)));
typedef __bf16 bf16x4 __attribute__((ext_vector_type(4)));
typedef float  f32x4  __attribute__((ext_vector_type(4)));

// ---------------------------------------------------------------------------
// Kernel 1: compose Wc = W2 @ W1 (fp32 math -> bf16), bc = W2 @ b1 + b2.
// The reference has NO activation between the two 1x1 convs, so they fuse
// into one: proj(t) = Wc t + bc. 3x fewer FLOPs, no H intermediate at all.
// ---------------------------------------------------------------------------
__global__ void compose_kernel(const float* __restrict__ W1, const float* __restrict__ W2,
                               const float* __restrict__ b1, const float* __restrict__ b2,
                               bf16_t* __restrict__ Wc, float* __restrict__ bc)
{
    const int g = blockIdx.x;            // 512
    const int c = threadIdx.x;           // 256
    const float* w2row = W2 + (size_t)g * HID;
    float s0 = 0.f, s1 = 0.f, s2 = 0.f, s3 = 0.f;
    for (int h = 0; h < HID; h += 4) {   // 4 chains to break fma latency
        s0 = fmaf(w2row[h + 0], W1[(size_t)(h + 0) * CIN + c], s0);
        s1 = fmaf(w2row[h + 1], W1[(size_t)(h + 1) * CIN + c], s1);
        s2 = fmaf(w2row[h + 2], W1[(size_t)(h + 2) * CIN + c], s2);
        s3 = fmaf(w2row[h + 3], W1[(size_t)(h + 3) * CIN + c], s3);
    }
    Wc[(size_t)g * CIN + c] = (bf16_t)((s0 + s1) + (s2 + s3));
    if (c == 0) {
        float t0 = 0.f, t1 = 0.f;
        for (int h = 0; h < HID; h += 2) {
            t0 = fmaf(w2row[h], b1[h], t0);
            t1 = fmaf(w2row[h + 1], b1[h + 1], t1);
        }
        bc[g] = t0 + t1 + b2[g];
    }
}

// ---------------------------------------------------------------------------
// Kernel 2: fused single-GEMM + tanh-pair-product + row-reduction.
// 256 blocks x 1024 thr (16 waves), 8 consecutive 32-row tiles per block.
// Wave w owns output cols [w*32, w*32+32) (cj=0,1), rows 0..31 (ri=0,1 x
// l15), BOTH pipes. acc = 32 AGPR. Ledger: 32 acc + psum 8 + bcv 8 + w 8 +
// frags 8 + v[4] 16 + addr ~20 = ~100 <= 128 cap (the R2-R10 rule: 16
// waves/CU needs total <= 128). A-only LDS, double-buffered: 2 x 32 KB.
// Per tile: [issue loads t+1] gemm(8 kk) tanh->psum [write t+1] barrier.
// One barrier per tile; prefetch HBM latency hides under the gemm.
// Swapped-operand MFMA (R7-proven): g = col0+cj*16+l4*4+r2, x-row = l15,
// rows summed into psum in-register + shfl over l15 at the end.
// ---------------------------------------------------------------------------
__global__ __launch_bounds__(1024, 4)
void fused_kernel(const float* __restrict__ x, const float* __restrict__ y,
                  const bf16_t* __restrict__ Wc, const float* __restrict__ bc,
                  float* __restrict__ partial)
{
    __shared__ char U[65536];            // 2 bufs x (2 pipes x 32 rows x 512 B)

    const int tid  = threadIdx.x;
    const int lane = tid & 63;
    const int wv   = tid >> 6;           // wave 0..15
    const int l15  = lane & 15;
    const int l4   = lane >> 4;
    const int col0 = wv * 32;

    // staging identity: threads 0-511 stage x, 512-1023 stage y; 16 thr/row
    const int sp   = tid >> 9;
    const int t9   = tid & 511;
    const int sr   = t9 >> 4;            // row 0..31
    const int sq   = t9 & 15;            // float4 slot
    const unsigned sswz   = (unsigned)((sr & 15) << 4);
    const unsigned sldsoff = (unsigned)(sp * 16384 + sr * 512);

    const float* sptr = (sp ? y : x) + ((size_t)(blockIdx.x * TPB) * TL + sr) * CIN;

    float4 v[4];
    auto sload = [&](const float* rowbase) {
        const float4* s4 = reinterpret_cast<const float4*>(rowbase);
#pragma unroll
        for (int c = 0; c < 4; ++c) v[c] = s4[sq + 16 * c];
    };
    auto swrite = [&](int buf) {
        char* p = U + (unsigned)(buf * 32768) + sldsoff;
#pragma unroll
        for (int c = 0; c < 4; ++c) {
            const int f = sq + 16 * c;
            bf16x4 h;
            h[0] = (bf16_t)v[c].x; h[1] = (bf16_t)v[c].y;
            h[2] = (bf16_t)v[c].z; h[3] = (bf16_t)v[c].w;
            *reinterpret_cast<bf16x4*>(p + (((unsigned)(8 * f)) ^ sswz)) = h;
        }
    };

    // bias fragments (bc, fp32) — folded into acc init each tile
    f32x4 bcv[2];
#pragma unroll
    for (int cj = 0; cj < 2; ++cj) {
        float4 t = *reinterpret_cast<const float4*>(bc + col0 + cj * 16 + l4 * 4);
        bcv[cj] = (f32x4){t.x, t.y, t.z, t.w};
    }

    // fragment LDS offsets: row r=ri*16+l15 (per pipe), byte within row =
    // (kk*64 + l4*16) ^ ((r&15)<<4)  [R7/R10-proven swizzle]
    unsigned fbase[2];
#pragma unroll
    for (int ri = 0; ri < 2; ++ri) {
        const int r = ri * 16 + l15;
        fbase[ri] = (unsigned)(r * 512) + (((unsigned)(l4 * 16)) ^ ((unsigned)((r & 15) << 4)));
    }

    f32x4 psum[2];
    psum[0] = (f32x4){0.f, 0.f, 0.f, 0.f};
    psum[1] = (f32x4){0.f, 0.f, 0.f, 0.f};

    // prologue: stage tile 0 into buf 0
    sload(sptr);
    swrite(0);
    __syncthreads();

    int cur = 0;
    for (int t = 0; t < TPB; ++t) {
        if (t + 1 < TPB) {               // issue tile t+1 loads early (T14)
            sptr += TL * CIN;
            sload(sptr);
        }

        f32x4 accx[2][2], accy[2][2];
#pragma unroll
        for (int ri = 0; ri < 2; ++ri)
#pragma unroll
            for (int cj = 0; cj < 2; ++cj) { accx[ri][cj] = bcv[cj]; accy[ri][cj] = bcv[cj]; }

        for (int kk = 0; kk < CIN / 32; ++kk) {
            bf16x8 w[2];
#pragma unroll
            for (int cj = 0; cj < 2; ++cj)
                w[cj] = *reinterpret_cast<const bf16x8*>(
                    Wc + (size_t)(col0 + cj * 16 + l15) * CIN + kk * 32 + l4 * 8);
            __builtin_amdgcn_s_setprio(1);
#pragma unroll
            for (int ri = 0; ri < 2; ++ri) {
                const unsigned o = (unsigned)(cur * 32768) + (fbase[ri] ^ (unsigned)(kk << 6));
                bf16x8 ax = *reinterpret_cast<const bf16x8*>(U + o);
                bf16x8 ay = *reinterpret_cast<const bf16x8*>(U + 16384u + o);
#pragma unroll
                for (int cj = 0; cj < 2; ++cj) {
                    accx[ri][cj] = __builtin_amdgcn_mfma_f32_16x16x32_bf16(w[cj], ax, accx[ri][cj], 0, 0, 0);
                    accy[ri][cj] = __builtin_amdgcn_mfma_f32_16x16x32_bf16(w[cj], ay, accy[ri][cj], 0, 0, 0);
                }
            }
            __builtin_amdgcn_s_setprio(0);
        }

        // paired tanh product, accumulated over ri and tiles into psum.
        // tanh(a)tanh(b) = (Ea-1)(Eb-1)/((Ea+1)(Eb+1)), E = e^{2v} clamped.
#pragma unroll
        for (int ri = 0; ri < 2; ++ri)
#pragma unroll
            for (int cj = 0; cj < 2; ++cj)
#pragma unroll
                for (int r2 = 0; r2 < 4; ++r2) {
                    float a = fminf(fmaxf(accx[ri][cj][r2], -9.0f), 9.0f);
                    float c = fminf(fmaxf(accy[ri][cj][r2], -9.0f), 9.0f);
                    float Ea = exp2f(a * 2.885390081777927f);
                    float Eb = exp2f(c * 2.885390081777927f);
                    float num = (Ea - 1.0f) * (Eb - 1.0f);
                    float den = (Ea + 1.0f) * (Eb + 1.0f);
                    psum[cj][r2] += num * __builtin_amdgcn_rcpf(den);
                }

        if (t + 1 < TPB) swrite(cur ^ 1);  // write-late into the idle buffer
        __syncthreads();
        cur ^= 1;
    }

    // reduce rows over the 16 l15 lanes (bits 0-3 only; l4 = g-chunk!)
#pragma unroll
    for (int cj = 0; cj < 2; ++cj)
#pragma unroll
        for (int r2 = 0; r2 < 4; ++r2) {
            float s = psum[cj][r2];
            s += __shfl_xor(s, 1);
            s += __shfl_xor(s, 2);
            s += __shfl_xor(s, 4);
            s += __shfl_xor(s, 8);
            psum[cj][r2] = s;
        }
    if (l15 == 0) {
#pragma unroll
        for (int cj = 0; cj < 2; ++cj) {
            float4 o4 = make_float4(psum[cj][0], psum[cj][1], psum[cj][2], psum[cj][3]);
            *reinterpret_cast<float4*>(partial + (size_t)blockIdx.x * HID + col0 + cj * 16 + l4 * 4) = o4;
        }
    }
}

// ---------------------------------------------------------------------------
// Kernel 3: sum the 8 block-partials per batch -> out[B][HID]
// ---------------------------------------------------------------------------
__global__ void reduce_kernel(const float* __restrict__ partial, float* __restrict__ out)
{
    int b = blockIdx.x;                  // 32
    int g = threadIdx.x;                 // 512
    float s = 0.f;
#pragma unroll
    for (int k = 0; k < TPB; ++k)
        s += partial[((size_t)(b * TPB + k)) * HID + g];
    out[b * HID + g] = s;
}

extern "C" void kernel_launch(void* const* d_in, const int* in_sizes, int n_in,
                              void* d_out, int out_size, void* d_ws, size_t ws_size,
                              hipStream_t stream)
{
    const float* x  = (const float*)d_in[0];
    const float* y  = (const float*)d_in[1];
    const float* W1 = (const float*)d_in[2];
    const float* b1 = (const float*)d_in[3];
    const float* W2 = (const float*)d_in[4];
    const float* b2 = (const float*)d_in[5];
    float* out = (float*)d_out;

    char* ws = (char*)d_ws;
    bf16_t* Wc     = (bf16_t*)ws;                    // 256 KB
    float*  bc     = (float*)(ws + (256 << 10));     // 2 KB
    float*  partial = (float*)(ws + (264 << 10));    // 512 KB (256 blocks x 512)

    hipLaunchKernelGGL(compose_kernel, dim3(HID), dim3(CIN), 0, stream, W1, W2, b1, b2, Wc, bc);
    hipLaunchKernelGGL(fused_kernel, dim3(NBLK), dim3(1024), 0, stream, x, y, Wc, bc, partial);
    hipLaunchKernelGGL(reduce_kernel, dim3(B_), dim3(512), 0, stream, partial, out);
}